// Round 1
// baseline (26013.885 us; speedup 1.0000x reference)
//
#include <hip/hip_runtime.h>
#include <cstdint>
#include <cstddef>

#define T_SEQ 4096
#define HSZ   512
#define NGATE 2048   // 4*HSZ
#define NB    16     // blocks per direction in recurrence
#define HB    32     // h-elements per block (HSZ/NB)
#define DIN   1024

// ---------------- init: zero h double-buffers and seq flags (agent-scope) ----------------
__global__ void init_sync_kernel(float* hbuf, unsigned* seq) {
  int tid = threadIdx.x;
  for (int i = tid; i < 2*2*2*HSZ; i += blockDim.x)
    __hip_atomic_store(&hbuf[i], 0.f, __ATOMIC_RELAXED, __HIP_MEMORY_SCOPE_AGENT);
  if (tid < 2*2*NB)
    __hip_atomic_store(&seq[tid], 0u, __ATOMIC_RELAXED, __HIP_MEMORY_SCOPE_AGENT);
}

// ---------------- fp32 GEMM with bias: P[t,r] = sum_k X[t,k]*W[r,k] + bi[r] + bh[r] ----------------
// X row-major [4096,K], W row-major [2048,K] (both K-contiguous -> NT dot products)
__global__ __launch_bounds__(256, 2)
void gemm_bias_kernel(const float* __restrict__ Xf, const float* __restrict__ Xb,
                      const float* __restrict__ Wf, const float* __restrict__ Wb,
                      const float* __restrict__ bif, const float* __restrict__ bhf,
                      const float* __restrict__ bib, const float* __restrict__ bhb,
                      float* __restrict__ Pf, float* __restrict__ Pb, int K)
{
  const int dir = blockIdx.z;
  const float* X  = dir ? Xb  : Xf;
  const float* W  = dir ? Wb  : Wf;
  const float* bi = dir ? bib : bif;
  const float* bh = dir ? bhb : bhf;
  float* P        = dir ? Pb  : Pf;

  const int m0 = blockIdx.x * 128;
  const int n0 = blockIdx.y * 128;
  const int tid = threadIdx.x;
  const int lr = tid >> 1;          // 0..127 row within tile
  const int lk = (tid & 1) * 8;     // 0 or 8: k-offset within 16-chunk

  __shared__ float As[16*128];
  __shared__ float Bs[16*128];

  float acc[8][8];
  #pragma unroll
  for (int i = 0; i < 8; ++i)
    #pragma unroll
    for (int j = 0; j < 8; ++j) acc[i][j] = 0.f;

  for (int k0 = 0; k0 < K; k0 += 16) {
    const float4 a0 = *(const float4*)(X + (size_t)(m0+lr)*K + k0 + lk);
    const float4 a1 = *(const float4*)(X + (size_t)(m0+lr)*K + k0 + lk + 4);
    const float4 b0 = *(const float4*)(W + (size_t)(n0+lr)*K + k0 + lk);
    const float4 b1 = *(const float4*)(W + (size_t)(n0+lr)*K + k0 + lk + 4);
    __syncthreads();
    As[(lk+0)*128+lr]=a0.x; As[(lk+1)*128+lr]=a0.y; As[(lk+2)*128+lr]=a0.z; As[(lk+3)*128+lr]=a0.w;
    As[(lk+4)*128+lr]=a1.x; As[(lk+5)*128+lr]=a1.y; As[(lk+6)*128+lr]=a1.z; As[(lk+7)*128+lr]=a1.w;
    Bs[(lk+0)*128+lr]=b0.x; Bs[(lk+1)*128+lr]=b0.y; Bs[(lk+2)*128+lr]=b0.z; Bs[(lk+3)*128+lr]=b0.w;
    Bs[(lk+4)*128+lr]=b1.x; Bs[(lk+5)*128+lr]=b1.y; Bs[(lk+6)*128+lr]=b1.z; Bs[(lk+7)*128+lr]=b1.w;
    __syncthreads();
    #pragma unroll
    for (int kk = 0; kk < 16; ++kk) {
      const float4 A0 = *(const float4*)(As + kk*128 + (tid&15)*8);
      const float4 A1 = *(const float4*)(As + kk*128 + (tid&15)*8 + 4);
      const float4 B0 = *(const float4*)(Bs + kk*128 + (tid>>4)*8);
      const float4 B1 = *(const float4*)(Bs + kk*128 + (tid>>4)*8 + 4);
      const float av[8] = {A0.x,A0.y,A0.z,A0.w,A1.x,A1.y,A1.z,A1.w};
      const float bv[8] = {B0.x,B0.y,B0.z,B0.w,B1.x,B1.y,B1.z,B1.w};
      #pragma unroll
      for (int i = 0; i < 8; ++i)
        #pragma unroll
        for (int j = 0; j < 8; ++j) acc[i][j] += av[i]*bv[j];
    }
  }
  const int tm = m0 + (tid&15)*8;
  const int tn = n0 + (tid>>4)*8;
  #pragma unroll
  for (int i = 0; i < 8; ++i) {
    #pragma unroll
    for (int j = 0; j < 8; ++j) {
      const int n = tn + j;
      P[(size_t)(tm+i)*NGATE + n] = acc[i][j] + bi[n] + bh[n];
    }
  }
}

// ---------------- persistent recurrence: one layer, both directions ----------------
// Block b (of NB per direction) owns h-indices [b*32, b*32+32) -> 128 rows of Whh
// (4 gates x 32), held in VGPRs (32 x float4 per lane).
// Lane layout: wave wv (0..7): cc = wv>>1 selects 128-col chunk, (wv&1)*64+lane = local row.
// Per step: broadcast h via LDS (wave-uniform ds_read_b128), partial dot per lane,
// LDS reduce over the 4 col-chunks, gate math on 32 lanes, publish h via agent-scope
// store + per-block seq flag; other blocks spin on the flags (sc1 loads).
__global__ __launch_bounds__(512, 2)
void recur_kernel(const float* __restrict__ Whh_f, const float* __restrict__ Whh_b,
                  const float* __restrict__ P_f, const float* __restrict__ P_b,
                  int prevf, int prevb,
                  float* hb_f, float* hb_b,
                  unsigned* seq_f, unsigned* seq_b,
                  float* y_f, float* y_b,
                  int y_stride, int y_off_f, int y_off_b, int y_rev_f, int y_rev_b,
                  float* out, int layer)
{
  const int dir = blockIdx.y;
  const float* Whh = dir ? Whh_b : Whh_f;
  const float* P   = dir ? P_b   : P_f;
  const int prev   = dir ? prevb : prevf;
  float* hb        = dir ? hb_b  : hb_f;
  unsigned* seq    = dir ? seq_b : seq_f;
  float* y         = dir ? y_b   : y_f;
  const int y_off  = dir ? y_off_b : y_off_f;
  const int y_rev  = dir ? y_rev_b : y_rev_f;

  const int b    = blockIdx.x;
  const int tid  = threadIdx.x;
  const int wv   = tid >> 6;
  const int lane = tid & 63;
  const int cc   = wv >> 1;                    // column chunk 0..3 (wave-uniform)
  const int row_local = (wv & 1)*64 + lane;    // 0..127
  const int gate = row_local >> 5;
  const int k    = row_local & 31;
  const int grow = gate*HSZ + b*HB + k;        // global gate-row

  __shared__ float h_lds[HSZ];
  __shared__ float part[4*128];
  __shared__ float gates[128];

  // Whh slice -> registers (one-time): 128 floats per lane
  float4 w[32];
  {
    const float4* wp = (const float4*)(Whh + (size_t)grow*HSZ + cc*128);
    #pragma unroll
    for (int j = 0; j < 32; ++j) w[j] = wp[j];
  }

  float creg = 0.f;   // cell state, owned by lanes tid<32

  for (int t = 0; t < T_SEQ; ++t) {
    // wait until all blocks of this direction published h for step t
    if (t > 0 && tid < NB) {
      while (__hip_atomic_load(&seq[tid], __ATOMIC_RELAXED, __HIP_MEMORY_SCOPE_AGENT)
             < (unsigned)t) {}
    }
    __syncthreads();
    // stage h (coherent sc1 loads) + prefetch input projection
    const float hv = __hip_atomic_load(&hb[(t&1)*HSZ + tid], __ATOMIC_RELAXED,
                                       __HIP_MEMORY_SCOPE_AGENT);
    float pv = 0.f;
    if (tid < 128) {
      const int te = prev ? (T_SEQ-1-t) : t;
      pv = P[(size_t)te*NGATE + grow];
    }
    h_lds[tid] = hv;
    __syncthreads();
    // matvec: lane covers 128 cols of one row; h read is wave-uniform -> LDS broadcast
    const float4* h4 = (const float4*)(h_lds + cc*128);
    float acc = 0.f;
    #pragma unroll
    for (int j = 0; j < 32; ++j) {
      const float4 hh = h4[j];
      acc += w[j].x*hh.x + w[j].y*hh.y + w[j].z*hh.z + w[j].w*hh.w;
    }
    part[cc*128 + row_local] = acc;
    __syncthreads();
    if (tid < 128) {
      gates[tid] = part[tid] + part[128+tid] + part[256+tid] + part[384+tid] + pv;
    }
    __syncthreads();
    if (tid < HB) {
      const float ig = gates[tid], fg = gates[32+tid], gg = gates[64+tid], og = gates[96+tid];
      const float i_s = 1.f/(1.f + __expf(-ig));
      const float f_s = 1.f/(1.f + __expf(-fg));
      const float o_s = 1.f/(1.f + __expf(-og));
      creg = f_s*creg + i_s*tanhf(gg);
      const float hnew = o_s*tanhf(creg);
      const int hidx = b*HB + tid;
      __hip_atomic_store(&hb[((t+1)&1)*HSZ + hidx], hnew, __ATOMIC_RELAXED,
                         __HIP_MEMORY_SCOPE_AGENT);
      const int trow = y_rev ? (T_SEQ-1-t) : t;
      y[(size_t)trow*y_stride + y_off + hidx] = hnew;
      if (t == T_SEQ-1) {
        out[layer*1024 + dir*HSZ + hidx]        = creg;   // cell_memories
        out[2048 + layer*1024 + dir*HSZ + hidx] = hnew;   // hidden_states
      }
    }
    // publish: drain this wave's stores (h stores are wave 0's), then bump seq flag
    if (tid == 0) {
      __builtin_amdgcn_s_waitcnt(0);
      __hip_atomic_store(&seq[b], (unsigned)(t+1), __ATOMIC_RELAXED,
                         __HIP_MEMORY_SCOPE_AGENT);
    }
  }
}

// ---------------- launch ----------------
extern "C" void kernel_launch(void* const* d_in, const int* in_sizes, int n_in,
                              void* d_out, int out_size, void* d_ws, size_t ws_size,
                              hipStream_t stream)
{
  const float* emb   = (const float*)d_in[0];
  const float* fWih0 = (const float*)d_in[1];
  const float* fWhh0 = (const float*)d_in[2];
  const float* fbih0 = (const float*)d_in[3];
  const float* fbhh0 = (const float*)d_in[4];
  const float* fWih1 = (const float*)d_in[5];
  const float* fWhh1 = (const float*)d_in[6];
  const float* fbih1 = (const float*)d_in[7];
  const float* fbhh1 = (const float*)d_in[8];
  const float* bWih0 = (const float*)d_in[9];
  const float* bWhh0 = (const float*)d_in[10];
  const float* bbih0 = (const float*)d_in[11];
  const float* bbhh0 = (const float*)d_in[12];
  const float* bWih1 = (const float*)d_in[13];
  const float* bWhh1 = (const float*)d_in[14];
  const float* bbih1 = (const float*)d_in[15];
  const float* bbhh1 = (const float*)d_in[16];
  float* out = (float*)d_out;

  // workspace layout (fp32): P[2][4096][2048] (67 MB, reused by both layers),
  // x1[2][4096][512] (17 MB), h double-buffers [2][2][2][512], seq flags [2][2][16]
  float* P_f  = (float*)d_ws;
  float* P_b  = P_f + (size_t)T_SEQ*NGATE;
  float* x1_f = P_b + (size_t)T_SEQ*NGATE;
  float* x1_b = x1_f + (size_t)T_SEQ*HSZ;
  float* hbuf = x1_b + (size_t)T_SEQ*HSZ;
  unsigned* seq = (unsigned*)(hbuf + 2*2*2*HSZ);

  init_sync_kernel<<<1, 512, 0, stream>>>(hbuf, seq);

  // layer 0 input projections (X = emb for both dirs; bwd reads P reversed in time)
  gemm_bias_kernel<<<dim3(32,16,2), 256, 0, stream>>>(
      emb, emb, fWih0, bWih0, fbih0, fbhh0, bbih0, bbhh0, P_f, P_b, DIN);

  recur_kernel<<<dim3(NB,2), 512, 0, stream>>>(
      fWhh0, bWhh0, P_f, P_b, /*prev_f=*/0, /*prev_b=*/1,
      hbuf + 0*1024, hbuf + 1*1024,
      seq + 0, seq + NB,
      x1_f, x1_b, /*y_stride=*/HSZ, /*off*/0, 0, /*rev*/0, 0,
      out, /*layer=*/0);

  // layer 1 input projections (X = layer-0 outputs, already in processing order)
  gemm_bias_kernel<<<dim3(32,16,2), 256, 0, stream>>>(
      x1_f, x1_b, fWih1, bWih1, fbih1, fbhh1, bbih1, bbhh1, P_f, P_b, HSZ);

  recur_kernel<<<dim3(NB,2), 512, 0, stream>>>(
      fWhh1, bWhh1, P_f, P_b, /*prev_f=*/0, /*prev_b=*/0,
      hbuf + 2*1024, hbuf + 3*1024,
      seq + 2*NB, seq + 3*NB,
      out + 4096, out + 4096, /*y_stride=*/1024, /*off*/0, HSZ, /*rev*/0, 1,
      out, /*layer=*/1);
}

// Round 2
// 9837.366 us; speedup vs baseline: 2.6444x; 2.6444x over previous
//
#include <hip/hip_runtime.h>
#include <cstdint>
#include <cstddef>

#define T_SEQ 4096
#define HSZ   512
#define NGATE 2048   // 4*HSZ
#define DIN   1024
#define NB0   16     // layer-0 blocks per direction
#define HB0   32     // h-elements per layer-0 block
#define NB1   32     // layer-1 blocks per direction
#define HB1   16     // h-elements per layer-1 block
#define CH    132    // skewed LDS chunk stride (128 + 4)

typedef unsigned long long u64;
typedef unsigned int u32;

__device__ __forceinline__ u64 exld(const u64* p) {
  return __hip_atomic_load(p, __ATOMIC_RELAXED, __HIP_MEMORY_SCOPE_AGENT);
}
__device__ __forceinline__ void exst(u64* p, u64 v) {
  __hip_atomic_store(p, v, __ATOMIC_RELAXED, __HIP_MEMORY_SCOPE_AGENT);
}
__device__ __forceinline__ int pgld(const u32* p) {
  return (int)__hip_atomic_load(p, __ATOMIC_RELAXED, __HIP_MEMORY_SCOPE_AGENT);
}
__device__ __forceinline__ void pgst(u32* p, u32 v) {
  __hip_atomic_store(p, v, __ATOMIC_RELAXED, __HIP_MEMORY_SCOPE_AGENT);
}

// ---------------- init: zero exchange slots (epoch0 == h_0 == 0) + progress flags ----------------
__global__ void init_sync_kernel(u64* ex, u32* prog) {
  const int tid = blockIdx.x * blockDim.x + threadIdx.x;
  if (tid < 2 * 2 * 4 * HSZ) exst(&ex[tid], 0ull);
  if (tid < 2 * (NB0 + NB1)) pgst(&prog[tid], 0u);
}

// ---------------- fp32 GEMM with bias: P[t,r] = sum_k X[t,k]*W[r,k] + bi[r] + bh[r] ----------------
__global__ __launch_bounds__(256, 2)
void gemm_bias_kernel(const float* __restrict__ Xf, const float* __restrict__ Xb,
                      const float* __restrict__ Wf, const float* __restrict__ Wb,
                      const float* __restrict__ bif, const float* __restrict__ bhf,
                      const float* __restrict__ bib, const float* __restrict__ bhb,
                      float* __restrict__ Pf, float* __restrict__ Pb, int K)
{
  const int dir = blockIdx.z;
  const float* X  = dir ? Xb  : Xf;
  const float* W  = dir ? Wb  : Wf;
  const float* bi = dir ? bib : bif;
  const float* bh = dir ? bhb : bhf;
  float* P        = dir ? Pb  : Pf;

  const int m0 = blockIdx.x * 128;
  const int n0 = blockIdx.y * 128;
  const int tid = threadIdx.x;
  const int lr = tid >> 1;
  const int lk = (tid & 1) * 8;

  __shared__ float As[16*128];
  __shared__ float Bs[16*128];

  float acc[8][8];
  #pragma unroll
  for (int i = 0; i < 8; ++i)
    #pragma unroll
    for (int j = 0; j < 8; ++j) acc[i][j] = 0.f;

  for (int k0 = 0; k0 < K; k0 += 16) {
    const float4 a0 = *(const float4*)(X + (size_t)(m0+lr)*K + k0 + lk);
    const float4 a1 = *(const float4*)(X + (size_t)(m0+lr)*K + k0 + lk + 4);
    const float4 b0 = *(const float4*)(W + (size_t)(n0+lr)*K + k0 + lk);
    const float4 b1 = *(const float4*)(W + (size_t)(n0+lr)*K + k0 + lk + 4);
    __syncthreads();
    As[(lk+0)*128+lr]=a0.x; As[(lk+1)*128+lr]=a0.y; As[(lk+2)*128+lr]=a0.z; As[(lk+3)*128+lr]=a0.w;
    As[(lk+4)*128+lr]=a1.x; As[(lk+5)*128+lr]=a1.y; As[(lk+6)*128+lr]=a1.z; As[(lk+7)*128+lr]=a1.w;
    Bs[(lk+0)*128+lr]=b0.x; Bs[(lk+1)*128+lr]=b0.y; Bs[(lk+2)*128+lr]=b0.z; Bs[(lk+3)*128+lr]=b0.w;
    Bs[(lk+4)*128+lr]=b1.x; Bs[(lk+5)*128+lr]=b1.y; Bs[(lk+6)*128+lr]=b1.z; Bs[(lk+7)*128+lr]=b1.w;
    __syncthreads();
    #pragma unroll
    for (int kk = 0; kk < 16; ++kk) {
      const float4 A0 = *(const float4*)(As + kk*128 + (tid&15)*8);
      const float4 A1 = *(const float4*)(As + kk*128 + (tid&15)*8 + 4);
      const float4 B0 = *(const float4*)(Bs + kk*128 + (tid>>4)*8);
      const float4 B1 = *(const float4*)(Bs + kk*128 + (tid>>4)*8 + 4);
      const float av[8] = {A0.x,A0.y,A0.z,A0.w,A1.x,A1.y,A1.z,A1.w};
      const float bv[8] = {B0.x,B0.y,B0.z,B0.w,B1.x,B1.y,B1.z,B1.w};
      #pragma unroll
      for (int i = 0; i < 8; ++i)
        #pragma unroll
        for (int j = 0; j < 8; ++j) acc[i][j] += av[i]*bv[j];
    }
  }
  const int tm = m0 + (tid&15)*8;
  const int tn = n0 + (tid>>4)*8;
  #pragma unroll
  for (int i = 0; i < 8; ++i) {
    #pragma unroll
    for (int j = 0; j < 8; ++j) {
      const int n = tn + j;
      P[(size_t)(tm+i)*NGATE + n] = acc[i][j] + bi[n] + bh[n];
    }
  }
}

// ---------------- fused persistent recurrence: both layers, both directions, pipelined ----------------
// blocks [0,16): L0 fwd   [16,32): L0 bwd   [32,64): L1 fwd   [64,96): L1 bwd
// Exchange protocol: h element published as u64 = (epoch<<32)|float_bits into slot epoch&3.
// Readers poll the data directly (one LLC round trip, no flags on the critical path).
// Slot-overwrite safety: writers lazily require all consumers' progress >= t-2 (4-slot slack).
__global__ __launch_bounds__(512, 2)
void fused_recur_kernel(const float* __restrict__ Whh0_f, const float* __restrict__ Whh0_b,
                        const float* __restrict__ Wih1_f, const float* __restrict__ Whh1_f,
                        const float* __restrict__ bih1_f, const float* __restrict__ bhh1_f,
                        const float* __restrict__ Wih1_b, const float* __restrict__ Whh1_b,
                        const float* __restrict__ bih1_b, const float* __restrict__ bhh1_b,
                        const float* __restrict__ P_f, const float* __restrict__ P_b,
                        u64* ex0, u64* ex1, u32* prog0, u32* prog1,
                        float* __restrict__ out)
{
  const int bx  = blockIdx.x;
  const int tid = threadIdx.x;
  const int lane = tid & 63;
  const int wv   = tid >> 6;

  __shared__ float xh[8*CH];     // skewed chunks: bank-conflict-free wave-uniform b128 reads
  __shared__ float gates[128];

  if (bx < 2*NB0) {
    // ---------------- layer 0 ----------------
    const int dir = (bx >= NB0) ? 1 : 0;
    const int b   = bx - dir*NB0;
    const float* Whh = dir ? Whh0_b : Whh0_f;
    const float* P   = dir ? P_b    : P_f;
    u64* exS   = ex0 + (size_t)dir*4*HSZ;      // self exchange (also read by layer 1)
    u32* prS   = prog0 + dir*NB0;
    u32* prL1  = prog1 + dir*NB1;

    const int cc        = lane >> 4;             // col chunk 0..3
    const int row_local = wv*16 + (lane & 15);   // 0..127
    const int gate = row_local >> 5, k = row_local & 31;
    const int grow = gate*HSZ + b*HB0 + k;
    const bool wr  = (lane >> 4) == 0;           // row-sum writer lanes

    float4 w[32];
    {
      const float4* wp = (const float4*)(Whh + (size_t)grow*HSZ + cc*128);
      #pragma unroll
      for (int j = 0; j < 32; ++j) w[j] = wp[j];
    }

    float creg = 0.f;
    for (int t = 0; t < T_SEQ; ++t) {
      // slot-overwrite guard (lazy; consumers: L0 peers + L1 blocks of this dir)
      if (tid >= 64 && tid < 64+NB0)  { while (pgld(&prS[tid-64])  < t-2) {} }
      if (tid >= 96 && tid < 96+NB1)  { while (pgld(&prL1[tid-96]) < t-2) {} }
      // P prefetch for writer lanes
      float pv = 0.f;
      if (wr) {
        const int te = dir ? (T_SEQ-1-t) : t;
        pv = P[(size_t)te*NGATE + grow];
      }
      // poll h_t directly from exchange (epoch == t), stage to skewed LDS
      {
        const u64* sp = exS + (size_t)(t & 3)*HSZ + tid;
        u64 v;
        do { v = exld(sp); } while ((u32)(v >> 32) != (u32)t);
        xh[(tid>>7)*CH + (tid & 127)] = __uint_as_float((u32)v);
      }
      __syncthreads();
      // matvec: lane covers 128 cols (chunk cc) of its row
      const float4* h4 = (const float4*)(xh + cc*CH);
      float acc = 0.f;
      #pragma unroll
      for (int j = 0; j < 32; ++j) {
        const float4 hh = h4[j];
        acc += w[j].x*hh.x + w[j].y*hh.y + w[j].z*hh.z + w[j].w*hh.w;
      }
      acc += __shfl_xor(acc, 16);
      acc += __shfl_xor(acc, 32);
      if (wr) gates[row_local] = acc + pv;
      __syncthreads();
      if (tid < HB0) {
        const float ig = gates[tid], fg = gates[32+tid], gg = gates[64+tid], og = gates[96+tid];
        const float i_s = 1.f/(1.f + __expf(-ig));
        const float f_s = 1.f/(1.f + __expf(-fg));
        const float o_s = 1.f/(1.f + __expf(-og));
        creg = f_s*creg + i_s*tanhf(gg);
        const float hnew = o_s*tanhf(creg);
        const int hidx = b*HB0 + tid;
        const u64 pkt = ((u64)(u32)(t+1) << 32) | (u64)__float_as_uint(hnew);
        exst(exS + (size_t)((t+1) & 3)*HSZ + hidx, pkt);
        if (t == T_SEQ-1) {
          out[dir*HSZ + hidx]        = creg;   // cell_memories layer 0
          out[2048 + dir*HSZ + hidx] = hnew;   // hidden_states layer 0
        }
      }
      if (tid == 0) pgst(&prS[b], (u32)(t+1));
    }
  } else {
    // ---------------- layer 1 ----------------
    const int r   = bx - 2*NB0;
    const int dir = (r >= NB1) ? 1 : 0;
    const int b   = r - dir*NB1;
    const float* Wih = dir ? Wih1_b : Wih1_f;
    const float* Whh = dir ? Whh1_b : Whh1_f;
    const float* bi  = dir ? bih1_b : bih1_f;
    const float* bh  = dir ? bhh1_b : bhh1_f;
    u64* exX = ex0 + (size_t)dir*4*HSZ;          // x source = layer-0 outputs
    u64* exS = ex1 + (size_t)dir*4*HSZ;          // self h exchange
    u32* prS = prog1 + dir*NB1;

    const int sub       = lane >> 3;             // 0..7 col chunk (0-3: Wih/x, 4-7: Whh/h)
    const int row_local = wv*8 + (lane & 7);     // 0..63
    const int gate = row_local >> 4, k = row_local & 15;
    const int grow = gate*HSZ + b*HB1 + k;
    const bool wr  = (lane >> 3) == 0;

    float4 w[32];
    {
      const float* wsrc = (sub < 4) ? (Wih + (size_t)grow*HSZ + sub*128)
                                    : (Whh + (size_t)grow*HSZ + (sub-4)*128);
      const float4* wp = (const float4*)wsrc;
      #pragma unroll
      for (int j = 0; j < 32; ++j) w[j] = wp[j];
    }
    float brow = 0.f;
    if (wr) brow = bi[grow] + bh[grow];

    float creg = 0.f;
    for (int t = 0; t < T_SEQ; ++t) {
      // slot-overwrite guard (consumers of ex1: L1 peers of this dir)
      if (tid >= 64 && tid < 64+NB1) { while (pgld(&prS[tid-64]) < t-2) {} }
      // poll x_t (layer-0 publish, epoch t+1) and own h_t (epoch t)
      {
        const u64* px = exX + (size_t)((t+1) & 3)*HSZ + tid;
        const u64* ph = exS + (size_t)(t & 3)*HSZ + tid;
        float xv = 0.f, hv = 0.f;
        bool okx = false, okh = false;
        do {
          if (!okx) { u64 v = exld(px); if ((u32)(v >> 32) == (u32)(t+1)) { xv = __uint_as_float((u32)v); okx = true; } }
          if (!okh) { u64 v = exld(ph); if ((u32)(v >> 32) == (u32)t)     { hv = __uint_as_float((u32)v); okh = true; } }
        } while (!(okx && okh));
        xh[(tid>>7)*CH + (tid & 127)]       = xv;   // chunks 0..3
        xh[(4 + (tid>>7))*CH + (tid & 127)] = hv;   // chunks 4..7
      }
      __syncthreads();
      const float4* v4 = (const float4*)(xh + sub*CH);
      float acc = 0.f;
      #pragma unroll
      for (int j = 0; j < 32; ++j) {
        const float4 hh = v4[j];
        acc += w[j].x*hh.x + w[j].y*hh.y + w[j].z*hh.z + w[j].w*hh.w;
      }
      acc += __shfl_xor(acc, 8);
      acc += __shfl_xor(acc, 16);
      acc += __shfl_xor(acc, 32);
      if (wr) gates[row_local] = acc + brow;
      __syncthreads();
      if (tid < HB1) {
        const float ig = gates[tid], fg = gates[16+tid], gg = gates[32+tid], og = gates[48+tid];
        const float i_s = 1.f/(1.f + __expf(-ig));
        const float f_s = 1.f/(1.f + __expf(-fg));
        const float o_s = 1.f/(1.f + __expf(-og));
        creg = f_s*creg + i_s*tanhf(gg);
        const float hnew = o_s*tanhf(creg);
        const int hidx = b*HB1 + tid;
        const u64 pkt = ((u64)(u32)(t+1) << 32) | (u64)__float_as_uint(hnew);
        exst(exS + (size_t)((t+1) & 3)*HSZ + hidx, pkt);
        const int trow = dir ? (T_SEQ-1-t) : t;
        out[4096 + (size_t)trow*1024 + dir*HSZ + hidx] = hnew;   // top-layer outputs
        if (t == T_SEQ-1) {
          out[1024 + dir*HSZ + hidx]        = creg;   // cell_memories layer 1
          out[2048 + 1024 + dir*HSZ + hidx] = hnew;   // hidden_states layer 1
        }
      }
      if (tid == 0) pgst(&prS[b], (u32)(t+1));
    }
  }
}

// ---------------- launch ----------------
extern "C" void kernel_launch(void* const* d_in, const int* in_sizes, int n_in,
                              void* d_out, int out_size, void* d_ws, size_t ws_size,
                              hipStream_t stream)
{
  const float* emb   = (const float*)d_in[0];
  const float* fWih0 = (const float*)d_in[1];
  const float* fWhh0 = (const float*)d_in[2];
  const float* fbih0 = (const float*)d_in[3];
  const float* fbhh0 = (const float*)d_in[4];
  const float* fWih1 = (const float*)d_in[5];
  const float* fWhh1 = (const float*)d_in[6];
  const float* fbih1 = (const float*)d_in[7];
  const float* fbhh1 = (const float*)d_in[8];
  const float* bWih0 = (const float*)d_in[9];
  const float* bWhh0 = (const float*)d_in[10];
  const float* bbih0 = (const float*)d_in[11];
  const float* bbhh0 = (const float*)d_in[12];
  const float* bWih1 = (const float*)d_in[13];
  const float* bWhh1 = (const float*)d_in[14];
  const float* bbih1 = (const float*)d_in[15];
  const float* bbhh1 = (const float*)d_in[16];
  float* out = (float*)d_out;

  // workspace: P[2][4096][2048] fp32 (67 MB), exchange ex0/ex1 [2][4][512] u64, progress flags
  float* P_f = (float*)d_ws;
  float* P_b = P_f + (size_t)T_SEQ*NGATE;
  u64*   ex0 = (u64*)(P_b + (size_t)T_SEQ*NGATE);
  u64*   ex1 = ex0 + 2*4*HSZ;
  u32*   prog0 = (u32*)(ex1 + 2*4*HSZ);
  u32*   prog1 = prog0 + 2*NB0;

  init_sync_kernel<<<8, 1024, 0, stream>>>(ex0, prog0);

  // layer-0 input projections for both directions (bwd reads P reversed in time)
  gemm_bias_kernel<<<dim3(32,16,2), 256, 0, stream>>>(
      emb, emb, fWih0, bWih0, fbih0, fbhh0, bbih0, bbhh0, P_f, P_b, DIN);

  // fused pipelined recurrence: L0 fwd/bwd + L1 fwd/bwd in one persistent launch
  fused_recur_kernel<<<96, 512, 0, stream>>>(
      fWhh0, bWhh0,
      fWih1, fWhh1, fbih1, fbhh1,
      bWih1, bWhh1, bbih1, bbhh1,
      P_f, P_b, ex0, ex1, prog0, prog1, out);
}